// Round 13
// baseline (142.054 us; speedup 1.0000x reference)
//
#include <hip/hip_runtime.h>
#include <stdint.h>
#include <math.h>

#pragma clang fp contract(off)

#define N_ROWS 1048576
#define N_CLS  20
#define K_TOP  2000
#define CAND_MAX 8192
#define NBINS  4096
#define H_COPIES 4
#define DELTA_ULP 4096u
#define MAGIC 0x5AD0C0DEu

// scal slots (dwords) -- inside the zeroed region
#define SC_CNT   0
#define SC_MAXK  1
#define SC_DONE  2   // maskscan done-counter

// ws layout
static constexpr size_t OFF_MKEY = 0;                              // u32[N]          4 MB
static constexpr size_t OFF_CLS  = OFF_MKEY + 4ull * N_ROWS;       // u8[N]           1 MB
static constexpr size_t OFF_HIST = OFF_CLS + (size_t)N_ROWS;       // u32[4*4096] -- zero region start
static constexpr size_t OFF_SCAL = OFF_HIST + 4ull * H_COPIES * NBINS;  // u32[16]
static constexpr size_t OFF_GRP  = OFF_SCAL + 64;                  // u64[32]     -- zero region end (16464 dw)
static constexpr size_t OFF_ZIN  = OFF_GRP + 256;                  // u32[8] MAGIC words (reset by last kernel)
static constexpr size_t OFF_CAND = OFF_ZIN + 64;                   // u64[CAND_MAX]
static constexpr size_t OFF_MASK = OFF_CAND + 8ull * CAND_MAX;     // u64[K_TOP*32]

__device__ __forceinline__ uint32_t mono_key(float f) {
    uint32_t u = __float_as_uint(f);
    return u ^ ((u & 0x80000000u) ? 0xFFFFFFFFu : 0x80000000u);
}
__device__ __forceinline__ float mono_inv(uint32_t k) {
    uint32_t u = (k & 0x80000000u) ? (k ^ 0x80000000u) : ~k;
    return __uint_as_float(u);
}

// ---- D1: per-row max/argmax of logits -> mkey, cls, fused 12-bit histogram.
//      R12 fix: EXPLICIT memory-level parallelism. 2048 blocks (8 blocks/CU -> up to
//      32 waves/CU); each thread owns 2 rows and issues ALL 10 float4 loads into
//      named registers before any use (R12 post-mortem: compiler had minimized to
//      VGPR=16 and serialized the load stream -> 700 B/CU in flight -> 67us).
__global__ __launch_bounds__(256) void k_score(const float* __restrict__ logits,
                                               uint32_t* __restrict__ mkey,
                                               uint8_t* __restrict__ cls,
                                               uint32_t* __restrict__ hist,   // zero region base
                                               uint32_t* __restrict__ zin) {
    __shared__ uint32_t hh[NBINS];         // 16 KB
    int t = threadIdx.x, b = blockIdx.x;

    // zero phase: blocks 0..7 zero hist(16384 dw) + scal(16) + grp(64) via device atomics
    if (b < 8) {
        uint32_t zd = 0;
        for (int k = 0; k < 8; ++k) zd += atomicExch(&hist[(b * 256 + t) + k * 2048], 0u);
        if (b == 7 && t < 80) zd += atomicExch(&hist[16384 + t], 0u);
        asm volatile("" :: "v"(zd));
        asm volatile("s_waitcnt vmcnt(0)" ::: "memory");
        __syncthreads();
        if (t == 0) atomicExch(&zin[b], MAGIC);
    }

    for (int i = t; i < NBINS; i += 256) hh[i] = 0;
    __syncthreads();

    // two rows per thread: rowA = base+t, rowB = base+256+t; all 10 loads up front
    size_t rowA = (size_t)b * 512 + t;
    size_t rowB = rowA + 256;
    const float4* pA = (const float4*)(logits + rowA * N_CLS);
    const float4* pB = (const float4*)(logits + rowB * N_CLS);
    float4 a0 = pA[0], a1 = pA[1], a2 = pA[2], a3 = pA[3], a4 = pA[4];
    float4 b0 = pB[0], b1 = pB[1], b2 = pB[2], b3 = pB[3], b4 = pB[4];

#define CK(mm, cc, val, idx) if ((val) > mm) { mm = (val); cc = (idx); }
    float mA = a0.x; int cA = 0;
    CK(mA, cA, a0.y, 1)  CK(mA, cA, a0.z, 2)  CK(mA, cA, a0.w, 3)
    CK(mA, cA, a1.x, 4)  CK(mA, cA, a1.y, 5)  CK(mA, cA, a1.z, 6)  CK(mA, cA, a1.w, 7)
    CK(mA, cA, a2.x, 8)  CK(mA, cA, a2.y, 9)  CK(mA, cA, a2.z, 10) CK(mA, cA, a2.w, 11)
    CK(mA, cA, a3.x, 12) CK(mA, cA, a3.y, 13) CK(mA, cA, a3.z, 14) CK(mA, cA, a3.w, 15)
    CK(mA, cA, a4.x, 16) CK(mA, cA, a4.y, 17) CK(mA, cA, a4.z, 18) CK(mA, cA, a4.w, 19)
    float mB = b0.x; int cB = 0;
    CK(mB, cB, b0.y, 1)  CK(mB, cB, b0.z, 2)  CK(mB, cB, b0.w, 3)
    CK(mB, cB, b1.x, 4)  CK(mB, cB, b1.y, 5)  CK(mB, cB, b1.z, 6)  CK(mB, cB, b1.w, 7)
    CK(mB, cB, b2.x, 8)  CK(mB, cB, b2.y, 9)  CK(mB, cB, b2.z, 10) CK(mB, cB, b2.w, 11)
    CK(mB, cB, b3.x, 12) CK(mB, cB, b3.y, 13) CK(mB, cB, b3.z, 14) CK(mB, cB, b3.w, 15)
    CK(mB, cB, b4.x, 16) CK(mB, cB, b4.y, 17) CK(mB, cB, b4.z, 18) CK(mB, cB, b4.w, 19)
#undef CK

    uint32_t uA = mono_key(mA), uB = mono_key(mB);
    mkey[rowA] = uA;  cls[rowA] = (uint8_t)cA;
    mkey[rowB] = uB;  cls[rowB] = (uint8_t)cB;
    atomicAdd(&hh[uA >> 20], 1u);
    atomicAdd(&hh[uB >> 20], 1u);
    __syncthreads();

    // wait for zeroing (normally long done: zero ~1us << compute)
    for (;;) {
        int ok = 1;
        if (t < 8) ok = (atomicAdd(&zin[t], 0u) == MAGIC) ? 1 : 0;
        if (__syncthreads_count(ok) == 256) break;
        __builtin_amdgcn_s_sleep(16);
    }
    // publish nonzero bins only (4 spread copies); kernel-end drain handles visibility
    uint32_t cp = (uint32_t)((b & (H_COPIES - 1)) << 12);
    for (int i = 0; i < 16; ++i) {
        uint32_t v = hh[t * 16 + i];
        if (v) atomicAdd(&hist[cp + t * 16 + i], v);
    }
}

// ---- D2: per-block redundant 12-bit find -> Tk = (b*<<20) - DELTA_ULP (tie margin),
//      then compact candidates (mkey >= Tk). cand[] stores the FINAL sort key
//      ((~sigmoid_bits)<<32 | row) -- sigmoid computed here only for passing rows.
__global__ __launch_bounds__(256) void k_compact(const uint32_t* __restrict__ mkey,
                                                 const uint32_t* __restrict__ hist,
                                                 uint32_t* __restrict__ scal,
                                                 unsigned long long* __restrict__ cand) {
    __shared__ uint32_t sfx[256];
    __shared__ uint32_t sTk;
    __shared__ uint32_t cnt, gbase;
    __shared__ uint64_t stg[1024];
    int t = threadIdx.x;
    int lane = t & 63;
    if (t == 0) cnt = 0;

    // find12: thread t owns bins [t*16, t*16+16), summed over 4 copies; suffix-scan
    // over 256 chunk totals; locate rank-K bin.
    uint32_t bv[16]; uint32_t ct = 0;
#pragma unroll
    for (int i = 0; i < 16; ++i) {
        uint32_t s = 0;
#pragma unroll
        for (int k = 0; k < H_COPIES; ++k) s += hist[(k << 12) + t * 16 + i];
        bv[i] = s; ct += s;
    }
    sfx[t] = ct;
    __syncthreads();
    for (int off = 1; off < 256; off <<= 1) {
        uint32_t v = (t + off < 256) ? sfx[t + off] : 0;
        __syncthreads();
        sfx[t] += v;
        __syncthreads();
    }
    if (sfx[t] >= (uint32_t)K_TOP && (t == 255 || sfx[t + 1] < (uint32_t)K_TOP)) {
        uint32_t cum = (t == 255) ? 0u : sfx[t + 1];
        int i = 15;
        for (; i >= 0; --i) { cum += bv[i]; if (cum >= (uint32_t)K_TOP) break; }
        if (i < 0) i = 0;
        uint32_t bstar = (uint32_t)(t * 16 + i);
        uint32_t tk = bstar << 20;
        // δ-ULP margin: covers rounded-sigmoid ties (~11 key-ULPs) with 370x slack.
        sTk = (tk > DELTA_ULP) ? (tk - DELTA_ULP) : 0u;
    }
    __syncthreads();
    uint32_t Tk = sTk;

    const uint4* m4 = (const uint4*)mkey;
    size_t base = (size_t)blockIdx.x * 1024;       // uint4 index; 4096 rows/block
    for (int it = 0; it < 4; ++it) {
        uint32_t r0 = (uint32_t)((base + it * 256 + t) * 4);
        uint4 v = m4[base + it * 256 + t];
#pragma unroll
        for (int e = 0; e < 4; ++e) {
            uint32_t u = (e == 0) ? v.x : (e == 1) ? v.y : (e == 2) ? v.z : v.w;
            bool pass = u >= Tk;
            unsigned long long bal = __ballot(pass);
            if (bal) {
                uint32_t wbase = 0;
                if (lane == 0) wbase = atomicAdd(&cnt, (uint32_t)__popcll(bal));
                wbase = __shfl(wbase, 0);
                if (pass) {
                    uint32_t pos = wbase + (uint32_t)__popcll(bal & ((1ull << lane) - 1ull));
                    if (pos < 1024) {
                        float m = mono_inv(u);
                        float ef = (float)exp(-(double)m);   // ~correctly-rounded fp32 expf
                        float s = 1.0f / (1.0f + ef);
                        stg[pos] = ((uint64_t)(~__float_as_uint(s)) << 32) | (r0 + e);
                    }
                }
            }
        }
    }
    __syncthreads();
    uint32_t n = cnt; if (n > 1024) n = 1024;
    if (t == 0 && n) gbase = atomicAdd(&scal[SC_CNT], n);
    __syncthreads();
    if (n) {
        uint32_t gb = gbase;
        for (uint32_t i = t; i < n; i += 256) {
            uint32_t pos = gb + i;
            if (pos < (uint32_t)CAND_MAX) cand[pos] = stg[i];  // plain store; boundary = coherence
        }
    }
}

// ---- D3: rank-by-counting, M-insensitive (proven R11): cand[] already holds final
//      keys -> LDS fill is a straight copy. 256 blocks x 4 waves; inner scan 4-way
//      unrolled for LDS ILP.
__global__ __launch_bounds__(256) void k_rank(const unsigned long long* __restrict__ cand,
                                              uint32_t* __restrict__ scal,
                                              const float* __restrict__ deltas,
                                              const float* __restrict__ locs,
                                              const int* __restrict__ stridep,
                                              const uint8_t* __restrict__ cls,
                                              float* __restrict__ out) {
    __shared__ uint64_t keys[CAND_MAX];   // 64 KB
    int t = threadIdx.x;
    uint32_t M = scal[SC_CNT];
    if (M > (uint32_t)CAND_MAX) M = CAND_MAX;
    for (uint32_t i = t; i < M; i += 256) keys[i] = cand[i];
    __syncthreads();
    int wid = t >> 6, lane = t & 63;
    float stridef = (float)(*stridep);
    float wmx = -3.4e38f;
    for (uint32_t c = (uint32_t)blockIdx.x * 4 + wid; c < M; c += 1024) {
        uint64_t myk = keys[c];
        uint32_t r = 0;
        uint32_t j = lane;
        for (; j + 192 < M; j += 256) {             // 4 independent LDS reads -> pipelined
            uint64_t k0 = keys[j], k1 = keys[j + 64], k2 = keys[j + 128], k3 = keys[j + 192];
            r += (uint32_t)(k0 < myk) + (uint32_t)(k1 < myk)
               + (uint32_t)(k2 < myk) + (uint32_t)(k3 < myk);
        }
        for (; j < M; j += 64) r += (keys[j] < myk) ? 1u : 0u;
#pragma unroll
        for (int o = 32; o > 0; o >>= 1) r += __shfl_down(r, o);
        if (lane == 0 && r < (uint32_t)K_TOP) {
            uint32_t row = (uint32_t)myk & (N_ROWS - 1);
            float s = __uint_as_float(~(uint32_t)(myk >> 32));
            float4 dl = ((const float4*)deltas)[row];
            float2 lc = ((const float2*)locs)[row];
            float d0 = dl.x * stridef, d1 = dl.y * stridef, d2 = dl.z * stridef, d3 = dl.w * stridef;
            float b0f = lc.x - d0, b1f = lc.y - d1, b2f = lc.x + d2, b3f = lc.y + d3;
            float4 bx = { b0f, b1f, b2f, b3f };
            *(float4*)&out[4 * r] = bx;
            out[8000 + r] = s;
            out[10000 + r] = (float)cls[row];
            wmx = fmaxf(wmx, fmaxf(fmaxf(b0f, b1f), fmaxf(b2f, b3f)));
        }
    }
    if (lane == 0) atomicMax(&scal[SC_MAXK], mono_key(wmx));
}

// ---- D4: pairwise suppression mask (quirky IoU replicated exactly) + fused scan.
//      Skip-empty rows (grp-gated). Atomic-only handoff (proven R5/R7/R8). Tail: zin reset.
__global__ __launch_bounds__(256) void k_maskscan(const float* __restrict__ out_ro,
                                                  uint32_t* __restrict__ scal,
                                                  uint64_t* __restrict__ mask,
                                                  unsigned long long* __restrict__ grp,
                                                  uint32_t* __restrict__ zin,
                                                  float* __restrict__ out) {
    __shared__ uint64_t wb[4][32];
    __shared__ int lastdone;
    int t = threadIdx.x;
    int lane = t & 63;
    int wid = t >> 6;
    int i = blockIdx.x * 4 + wid;                   // 2000 waves total
    float off1 = mono_inv(scal[SC_MAXK]) + 1.0f;    // max_coord + 1 (prev dispatch, coherent)
    float4 boxi = *(const float4*)&out_ro[4 * i];
    float oi = out_ro[10000 + i] * off1;
    float x1i = boxi.x + oi, y2i = boxi.y + oi, x2i = boxi.z + oi, y1i = boxi.w + oi;
    float ai = (x2i - x1i) * (y2i - y1i);
    uint64_t any = 0;
    for (int jb = 0; jb < 32; ++jb) {
        int j = jb * 64 + lane;
        bool sup = false;
        if (j < K_TOP && j > i) {
            float4 boxj = *(const float4*)&out_ro[4 * j];
            float oj = out_ro[10000 + j] * off1;
            float x1j = boxj.x + oj, y2j = boxj.y + oj, x2j = boxj.z + oj, y1j = boxj.w + oj;
            float aj = (x2j - x1j) * (y2j - y1j);
            float xx1 = fmaxf(x1i, x1j);
            float yy1 = fminf(y1i, y1j);
            float xx2 = fminf(x2i, x2j);
            float yy2 = fmaxf(y2i, y2j);
            float inter = fabsf(xx2 - xx1) * fabsf(yy2 - yy1);
            float iou = inter / ((ai + aj) - inter);
            sup = iou > 0.5f;
        }
        unsigned long long bits = __ballot(sup);
        if (lane == 0) wb[wid][jb] = bits;
        any |= bits;
    }
    unsigned long long dummy = 0;
    if (lane == 0 && any) {                         // rare: NMS barely suppresses here
        for (int jb = 0; jb < 32; ++jb)
            dummy += atomicExch(&mask[(size_t)i * 32 + jb], wb[wid][jb]);
        dummy += atomicOr(&grp[i >> 6], 1ull << (i & 63));
    }
    asm volatile("" :: "v"(dummy));                 // force atomic returns (vmcnt drained)
    asm volatile("s_waitcnt vmcnt(0) lgkmcnt(0)" ::: "memory");
    __syncthreads();
    if (t == 0) {
        unsigned old = atomicAdd(&scal[SC_DONE], 1u);
        lastdone = (old == (unsigned)(gridDim.x - 1)) ? 1 : 0;
    }
    __syncthreads();
    if (!lastdone) return;

    if (t < 64) {
        int l = t;                                  // lane w<32 holds active word w
        uint64_t g = (l < 32) ? atomicOr(&grp[l], 0ull) : 0ull;
        uint64_t active = ~0ull;
        if (__ballot(g != 0ull)) {
            for (int gg = 0; gg < 32; ++gg) {
                uint64_t nz = __shfl(g, gg);
                while (nz) {
                    int b = __ffsll((long long)nz) - 1;
                    nz &= nz - 1;
                    int ii = gg * 64 + b;
                    uint64_t aw = __shfl(active, gg);
                    bool kept = (aw >> b) & 1ull;
                    uint64_t m = (l < 32) ? atomicOr(&mask[(size_t)ii * 32 + l], 0ull) : 0ull;
                    if (kept) active &= ~m;
                }
            }
        }
        if (l < 32) {
            int limit = K_TOP - l * 64;
            int nvec = limit < 64 ? limit / 4 : 16;
            for (int v = 0; v < nvec; ++v) {
                float4 f;
                f.x = ((active >> (4 * v + 0)) & 1ull) ? 1.0f : 0.0f;
                f.y = ((active >> (4 * v + 1)) & 1ull) ? 1.0f : 0.0f;
                f.z = ((active >> (4 * v + 2)) & 1ull) ? 1.0f : 0.0f;
                f.w = ((active >> (4 * v + 3)) & 1ull) ? 1.0f : 0.0f;
                *(float4*)&out[12000 + l * 64 + 4 * v] = f;
            }
        }
    }
    // reset MAGIC words for the next replay (zeroed state is what D1 expects)
    if (t < 8) atomicExch(&zin[t], 0u);
}

extern "C" void kernel_launch(void* const* d_in, const int* in_sizes, int n_in,
                              void* d_out, int out_size, void* d_ws, size_t ws_size,
                              hipStream_t stream) {
    const float* deltas = (const float*)d_in[0];
    const float* locs   = (const float*)d_in[1];
    const float* logits = (const float*)d_in[2];
    const int*   stridep = (const int*)d_in[3];
    float* out = (float*)d_out;
    char* ws = (char*)d_ws;

    uint32_t* mkey = (uint32_t*)(ws + OFF_MKEY);
    uint8_t*  cls  = (uint8_t*)(ws + OFF_CLS);
    uint32_t* hist = (uint32_t*)(ws + OFF_HIST);
    uint32_t* scal = (uint32_t*)(ws + OFF_SCAL);
    unsigned long long* grp = (unsigned long long*)(ws + OFF_GRP);
    uint32_t* zin  = (uint32_t*)(ws + OFF_ZIN);
    unsigned long long* cand = (unsigned long long*)(ws + OFF_CAND);
    uint64_t* mask = (uint64_t*)(ws + OFF_MASK);

    k_score<<<dim3(2048), dim3(256), 0, stream>>>(logits, mkey, cls, hist, zin);
    k_compact<<<dim3(256), dim3(256), 0, stream>>>(mkey, hist, scal, cand);
    k_rank<<<dim3(256), dim3(256), 0, stream>>>(cand, scal, deltas, locs, stridep, cls, out);
    k_maskscan<<<dim3(500), dim3(256), 0, stream>>>(out, scal, mask, grp, zin, out);
}

// Round 14
// 114.017 us; speedup vs baseline: 1.2459x; 1.2459x over previous
//
#include <hip/hip_runtime.h>
#include <stdint.h>
#include <math.h>

#pragma clang fp contract(off)

#define N_ROWS 1048576
#define N_CLS  20
#define K_TOP  2000
#define CAND_MAX 8192
#define NBINS  4096
#define H_COPIES 4
#define DELTA_ULP 4096u
#define MAGIC 0x5AD0C0DEu

// scal slots (dwords) -- inside the zeroed region
#define SC_CNT   0
#define SC_MAXK  1
#define SC_DONE  2   // maskscan done-counter

// ws layout
static constexpr size_t OFF_MKEY = 0;                              // u32[N]          4 MB
static constexpr size_t OFF_CLS  = OFF_MKEY + 4ull * N_ROWS;       // u8[N]           1 MB
static constexpr size_t OFF_HIST = OFF_CLS + (size_t)N_ROWS;       // u32[4*4096] -- zero region start
static constexpr size_t OFF_SCAL = OFF_HIST + 4ull * H_COPIES * NBINS;  // u32[16]
static constexpr size_t OFF_GRP  = OFF_SCAL + 64;                  // u64[32]     -- zero region end (16464 dw)
static constexpr size_t OFF_ZIN  = OFF_GRP + 256;                  // u32[8] MAGIC words (reset by last kernel)
static constexpr size_t OFF_CAND = OFF_ZIN + 64;                   // u64[CAND_MAX]
static constexpr size_t OFF_MASK = OFF_CAND + 8ull * CAND_MAX;     // u64[K_TOP*32]

__device__ __forceinline__ uint32_t mono_key(float f) {
    uint32_t u = __float_as_uint(f);
    return u ^ ((u & 0x80000000u) ? 0xFFFFFFFFu : 0x80000000u);
}
__device__ __forceinline__ float mono_inv(uint32_t k) {
    uint32_t u = (k & 0x80000000u) ? (k ^ 0x80000000u) : ~k;
    return __uint_as_float(u);
}

// ---- D1a: PURE read+argmax+write. Ablation of R3-R13's fused machinery: no LDS,
//      no atomics, no spin, no launch-bounds cap. All 20 float4 loads issued before
//      any use (sched_barrier(0) pins program order -> ~80 VGPRs of reads in flight).
__global__ __launch_bounds__(256) void k_scoremax(const float* __restrict__ logits,
                                                  uint32_t* __restrict__ mkey,
                                                  uint8_t* __restrict__ cls) {
    int t = threadIdx.x, b = blockIdx.x;
    size_t r0 = (size_t)b * 1024 + t;              // rows r0, +256, +512, +768
    const float4* p0 = (const float4*)(logits + r0 * N_CLS);
    const float4* p1 = (const float4*)(logits + (r0 + 256) * N_CLS);
    const float4* p2 = (const float4*)(logits + (r0 + 512) * N_CLS);
    const float4* p3 = (const float4*)(logits + (r0 + 768) * N_CLS);
    float4 a0 = p0[0], a1 = p0[1], a2 = p0[2], a3 = p0[3], a4 = p0[4];
    float4 b0 = p1[0], b1 = p1[1], b2 = p1[2], b3 = p1[3], b4 = p1[4];
    float4 c0 = p2[0], c1 = p2[1], c2 = p2[2], c3 = p2[3], c4 = p2[4];
    float4 d0 = p3[0], d1 = p3[1], d2 = p3[2], d3 = p3[3], d4 = p3[4];
    __builtin_amdgcn_sched_barrier(0);             // all 20 loads precede all uses

#define CK(mm, cc, val, idx) if ((val) > mm) { mm = (val); cc = (idx); }
    float mA = a0.x; int cA = 0;
    CK(mA, cA, a0.y, 1)  CK(mA, cA, a0.z, 2)  CK(mA, cA, a0.w, 3)
    CK(mA, cA, a1.x, 4)  CK(mA, cA, a1.y, 5)  CK(mA, cA, a1.z, 6)  CK(mA, cA, a1.w, 7)
    CK(mA, cA, a2.x, 8)  CK(mA, cA, a2.y, 9)  CK(mA, cA, a2.z, 10) CK(mA, cA, a2.w, 11)
    CK(mA, cA, a3.x, 12) CK(mA, cA, a3.y, 13) CK(mA, cA, a3.z, 14) CK(mA, cA, a3.w, 15)
    CK(mA, cA, a4.x, 16) CK(mA, cA, a4.y, 17) CK(mA, cA, a4.z, 18) CK(mA, cA, a4.w, 19)
    float mB = b0.x; int cB = 0;
    CK(mB, cB, b0.y, 1)  CK(mB, cB, b0.z, 2)  CK(mB, cB, b0.w, 3)
    CK(mB, cB, b1.x, 4)  CK(mB, cB, b1.y, 5)  CK(mB, cB, b1.z, 6)  CK(mB, cB, b1.w, 7)
    CK(mB, cB, b2.x, 8)  CK(mB, cB, b2.y, 9)  CK(mB, cB, b2.z, 10) CK(mB, cB, b2.w, 11)
    CK(mB, cB, b3.x, 12) CK(mB, cB, b3.y, 13) CK(mB, cB, b3.z, 14) CK(mB, cB, b3.w, 15)
    CK(mB, cB, b4.x, 16) CK(mB, cB, b4.y, 17) CK(mB, cB, b4.z, 18) CK(mB, cB, b4.w, 19)
    float mC = c0.x; int cC = 0;
    CK(mC, cC, c0.y, 1)  CK(mC, cC, c0.z, 2)  CK(mC, cC, c0.w, 3)
    CK(mC, cC, c1.x, 4)  CK(mC, cC, c1.y, 5)  CK(mC, cC, c1.z, 6)  CK(mC, cC, c1.w, 7)
    CK(mC, cC, c2.x, 8)  CK(mC, cC, c2.y, 9)  CK(mC, cC, c2.z, 10) CK(mC, cC, c2.w, 11)
    CK(mC, cC, c3.x, 12) CK(mC, cC, c3.y, 13) CK(mC, cC, c3.z, 14) CK(mC, cC, c3.w, 15)
    CK(mC, cC, c4.x, 16) CK(mC, cC, c4.y, 17) CK(mC, cC, c4.z, 18) CK(mC, cC, c4.w, 19)
    float mD = d0.x; int cD = 0;
    CK(mD, cD, d0.y, 1)  CK(mD, cD, d0.z, 2)  CK(mD, cD, d0.w, 3)
    CK(mD, cD, d1.x, 4)  CK(mD, cD, d1.y, 5)  CK(mD, cD, d1.z, 6)  CK(mD, cD, d1.w, 7)
    CK(mD, cD, d2.x, 8)  CK(mD, cD, d2.y, 9)  CK(mD, cD, d2.z, 10) CK(mD, cD, d2.w, 11)
    CK(mD, cD, d3.x, 12) CK(mD, cD, d3.y, 13) CK(mD, cD, d3.z, 14) CK(mD, cD, d3.w, 15)
    CK(mD, cD, d4.x, 16) CK(mD, cD, d4.y, 17) CK(mD, cD, d4.z, 18) CK(mD, cD, d4.w, 19)
#undef CK

    mkey[r0]       = mono_key(mA);  cls[r0]       = (uint8_t)cA;
    mkey[r0 + 256] = mono_key(mB);  cls[r0 + 256] = (uint8_t)cB;
    mkey[r0 + 512] = mono_key(mC);  cls[r0 + 512] = (uint8_t)cC;
    mkey[r0 + 768] = mono_key(mD);  cls[r0 + 768] = (uint8_t)cD;
}

// ---- D1b: 12-bit histogram from mkey (coalesced uint4 read) + the zero/zin/publish
//      machinery (moved here, away from the 80MB read stream).
__global__ __launch_bounds__(256) void k_hist(const uint32_t* __restrict__ mkey,
                                              uint32_t* __restrict__ hist,   // zero region base
                                              uint32_t* __restrict__ zin) {
    __shared__ uint32_t hh[NBINS];         // 16 KB
    int t = threadIdx.x, b = blockIdx.x;

    // zero phase: blocks 0..7 zero hist(16384 dw) + scal(16) + grp(64) via device atomics
    if (b < 8) {
        uint32_t zd = 0;
        for (int k = 0; k < 8; ++k) zd += atomicExch(&hist[(b * 256 + t) + k * 2048], 0u);
        if (b == 7 && t < 80) zd += atomicExch(&hist[16384 + t], 0u);
        asm volatile("" :: "v"(zd));
        asm volatile("s_waitcnt vmcnt(0)" ::: "memory");
        __syncthreads();
        if (t == 0) atomicExch(&zin[b], MAGIC);
    }

    for (int i = t; i < NBINS; i += 256) hh[i] = 0;
    __syncthreads();

    uint4 v = ((const uint4*)mkey)[(size_t)b * 256 + t];   // 4 keys/thread, coalesced
    atomicAdd(&hh[v.x >> 20], 1u);
    atomicAdd(&hh[v.y >> 20], 1u);
    atomicAdd(&hh[v.z >> 20], 1u);
    atomicAdd(&hh[v.w >> 20], 1u);
    __syncthreads();

    // wait for zeroing
    for (;;) {
        int ok = 1;
        if (t < 8) ok = (atomicAdd(&zin[t], 0u) == MAGIC) ? 1 : 0;
        if (__syncthreads_count(ok) == 256) break;
        __builtin_amdgcn_s_sleep(16);
    }
    // publish nonzero bins only (4 spread copies); kernel-end drain handles visibility
    uint32_t cp = (uint32_t)((b & (H_COPIES - 1)) << 12);
    for (int i = 0; i < 16; ++i) {
        uint32_t v2 = hh[t * 16 + i];
        if (v2) atomicAdd(&hist[cp + t * 16 + i], v2);
    }
}

// ---- D2: per-block redundant 12-bit find -> Tk = (b*<<20) - DELTA_ULP (tie margin),
//      then compact candidates (mkey >= Tk). cand[] stores the FINAL sort key
//      ((~sigmoid_bits)<<32 | row) -- sigmoid computed here only for passing rows.
__global__ __launch_bounds__(256) void k_compact(const uint32_t* __restrict__ mkey,
                                                 const uint32_t* __restrict__ hist,
                                                 uint32_t* __restrict__ scal,
                                                 unsigned long long* __restrict__ cand) {
    __shared__ uint32_t sfx[256];
    __shared__ uint32_t sTk;
    __shared__ uint32_t cnt, gbase;
    __shared__ uint64_t stg[1024];
    int t = threadIdx.x;
    int lane = t & 63;
    if (t == 0) cnt = 0;

    // find12: thread t owns bins [t*16, t*16+16), summed over 4 copies; suffix-scan
    // over 256 chunk totals; locate rank-K bin.
    uint32_t bv[16]; uint32_t ct = 0;
#pragma unroll
    for (int i = 0; i < 16; ++i) {
        uint32_t s = 0;
#pragma unroll
        for (int k = 0; k < H_COPIES; ++k) s += hist[(k << 12) + t * 16 + i];
        bv[i] = s; ct += s;
    }
    sfx[t] = ct;
    __syncthreads();
    for (int off = 1; off < 256; off <<= 1) {
        uint32_t v = (t + off < 256) ? sfx[t + off] : 0;
        __syncthreads();
        sfx[t] += v;
        __syncthreads();
    }
    if (sfx[t] >= (uint32_t)K_TOP && (t == 255 || sfx[t + 1] < (uint32_t)K_TOP)) {
        uint32_t cum = (t == 255) ? 0u : sfx[t + 1];
        int i = 15;
        for (; i >= 0; --i) { cum += bv[i]; if (cum >= (uint32_t)K_TOP) break; }
        if (i < 0) i = 0;
        uint32_t bstar = (uint32_t)(t * 16 + i);
        uint32_t tk = bstar << 20;
        // δ-ULP margin: covers rounded-sigmoid ties (~11 key-ULPs) with 370x slack.
        sTk = (tk > DELTA_ULP) ? (tk - DELTA_ULP) : 0u;
    }
    __syncthreads();
    uint32_t Tk = sTk;

    const uint4* m4 = (const uint4*)mkey;
    size_t base = (size_t)blockIdx.x * 1024;       // uint4 index; 4096 rows/block
    for (int it = 0; it < 4; ++it) {
        uint32_t r0 = (uint32_t)((base + it * 256 + t) * 4);
        uint4 v = m4[base + it * 256 + t];
#pragma unroll
        for (int e = 0; e < 4; ++e) {
            uint32_t u = (e == 0) ? v.x : (e == 1) ? v.y : (e == 2) ? v.z : v.w;
            bool pass = u >= Tk;
            unsigned long long bal = __ballot(pass);
            if (bal) {
                uint32_t wbase = 0;
                if (lane == 0) wbase = atomicAdd(&cnt, (uint32_t)__popcll(bal));
                wbase = __shfl(wbase, 0);
                if (pass) {
                    uint32_t pos = wbase + (uint32_t)__popcll(bal & ((1ull << lane) - 1ull));
                    if (pos < 1024) {
                        float m = mono_inv(u);
                        float ef = (float)exp(-(double)m);   // ~correctly-rounded fp32 expf
                        float s = 1.0f / (1.0f + ef);
                        stg[pos] = ((uint64_t)(~__float_as_uint(s)) << 32) | (r0 + e);
                    }
                }
            }
        }
    }
    __syncthreads();
    uint32_t n = cnt; if (n > 1024) n = 1024;
    if (t == 0 && n) gbase = atomicAdd(&scal[SC_CNT], n);
    __syncthreads();
    if (n) {
        uint32_t gb = gbase;
        for (uint32_t i = t; i < n; i += 256) {
            uint32_t pos = gb + i;
            if (pos < (uint32_t)CAND_MAX) cand[pos] = stg[i];  // plain store; boundary = coherence
        }
    }
}

// ---- D3: rank-by-counting, M-insensitive (proven R11): cand[] already holds final
//      keys -> LDS fill is a straight copy. 256 blocks x 4 waves; inner scan 4-way
//      unrolled for LDS ILP.
__global__ __launch_bounds__(256) void k_rank(const unsigned long long* __restrict__ cand,
                                              uint32_t* __restrict__ scal,
                                              const float* __restrict__ deltas,
                                              const float* __restrict__ locs,
                                              const int* __restrict__ stridep,
                                              const uint8_t* __restrict__ cls,
                                              float* __restrict__ out) {
    __shared__ uint64_t keys[CAND_MAX];   // 64 KB
    int t = threadIdx.x;
    uint32_t M = scal[SC_CNT];
    if (M > (uint32_t)CAND_MAX) M = CAND_MAX;
    for (uint32_t i = t; i < M; i += 256) keys[i] = cand[i];
    __syncthreads();
    int wid = t >> 6, lane = t & 63;
    float stridef = (float)(*stridep);
    float wmx = -3.4e38f;
    for (uint32_t c = (uint32_t)blockIdx.x * 4 + wid; c < M; c += 1024) {
        uint64_t myk = keys[c];
        uint32_t r = 0;
        uint32_t j = lane;
        for (; j + 192 < M; j += 256) {             // 4 independent LDS reads -> pipelined
            uint64_t k0 = keys[j], k1 = keys[j + 64], k2 = keys[j + 128], k3 = keys[j + 192];
            r += (uint32_t)(k0 < myk) + (uint32_t)(k1 < myk)
               + (uint32_t)(k2 < myk) + (uint32_t)(k3 < myk);
        }
        for (; j < M; j += 64) r += (keys[j] < myk) ? 1u : 0u;
#pragma unroll
        for (int o = 32; o > 0; o >>= 1) r += __shfl_down(r, o);
        if (lane == 0 && r < (uint32_t)K_TOP) {
            uint32_t row = (uint32_t)myk & (N_ROWS - 1);
            float s = __uint_as_float(~(uint32_t)(myk >> 32));
            float4 dl = ((const float4*)deltas)[row];
            float2 lc = ((const float2*)locs)[row];
            float d0 = dl.x * stridef, d1 = dl.y * stridef, d2 = dl.z * stridef, d3 = dl.w * stridef;
            float b0f = lc.x - d0, b1f = lc.y - d1, b2f = lc.x + d2, b3f = lc.y + d3;
            float4 bx = { b0f, b1f, b2f, b3f };
            *(float4*)&out[4 * r] = bx;
            out[8000 + r] = s;
            out[10000 + r] = (float)cls[row];
            wmx = fmaxf(wmx, fmaxf(fmaxf(b0f, b1f), fmaxf(b2f, b3f)));
        }
    }
    if (lane == 0) atomicMax(&scal[SC_MAXK], mono_key(wmx));
}

// ---- D4: pairwise suppression mask (quirky IoU replicated exactly) + fused scan.
//      Skip-empty rows (grp-gated). Atomic-only handoff (proven R5/R7/R8). Tail: zin reset.
__global__ __launch_bounds__(256) void k_maskscan(const float* __restrict__ out_ro,
                                                  uint32_t* __restrict__ scal,
                                                  uint64_t* __restrict__ mask,
                                                  unsigned long long* __restrict__ grp,
                                                  uint32_t* __restrict__ zin,
                                                  float* __restrict__ out) {
    __shared__ uint64_t wb[4][32];
    __shared__ int lastdone;
    int t = threadIdx.x;
    int lane = t & 63;
    int wid = t >> 6;
    int i = blockIdx.x * 4 + wid;                   // 2000 waves total
    float off1 = mono_inv(scal[SC_MAXK]) + 1.0f;    // max_coord + 1 (prev dispatch, coherent)
    float4 boxi = *(const float4*)&out_ro[4 * i];
    float oi = out_ro[10000 + i] * off1;
    float x1i = boxi.x + oi, y2i = boxi.y + oi, x2i = boxi.z + oi, y1i = boxi.w + oi;
    float ai = (x2i - x1i) * (y2i - y1i);
    uint64_t any = 0;
    for (int jb = 0; jb < 32; ++jb) {
        int j = jb * 64 + lane;
        bool sup = false;
        if (j < K_TOP && j > i) {
            float4 boxj = *(const float4*)&out_ro[4 * j];
            float oj = out_ro[10000 + j] * off1;
            float x1j = boxj.x + oj, y2j = boxj.y + oj, x2j = boxj.z + oj, y1j = boxj.w + oj;
            float aj = (x2j - x1j) * (y2j - y1j);
            float xx1 = fmaxf(x1i, x1j);
            float yy1 = fminf(y1i, y1j);
            float xx2 = fminf(x2i, x2j);
            float yy2 = fmaxf(y2i, y2j);
            float inter = fabsf(xx2 - xx1) * fabsf(yy2 - yy1);
            float iou = inter / ((ai + aj) - inter);
            sup = iou > 0.5f;
        }
        unsigned long long bits = __ballot(sup);
        if (lane == 0) wb[wid][jb] = bits;
        any |= bits;
    }
    unsigned long long dummy = 0;
    if (lane == 0 && any) {                         // rare: NMS barely suppresses here
        for (int jb = 0; jb < 32; ++jb)
            dummy += atomicExch(&mask[(size_t)i * 32 + jb], wb[wid][jb]);
        dummy += atomicOr(&grp[i >> 6], 1ull << (i & 63));
    }
    asm volatile("" :: "v"(dummy));                 // force atomic returns (vmcnt drained)
    asm volatile("s_waitcnt vmcnt(0) lgkmcnt(0)" ::: "memory");
    __syncthreads();
    if (t == 0) {
        unsigned old = atomicAdd(&scal[SC_DONE], 1u);
        lastdone = (old == (unsigned)(gridDim.x - 1)) ? 1 : 0;
    }
    __syncthreads();
    if (!lastdone) return;

    if (t < 64) {
        int l = t;                                  // lane w<32 holds active word w
        uint64_t g = (l < 32) ? atomicOr(&grp[l], 0ull) : 0ull;
        uint64_t active = ~0ull;
        if (__ballot(g != 0ull)) {
            for (int gg = 0; gg < 32; ++gg) {
                uint64_t nz = __shfl(g, gg);
                while (nz) {
                    int b = __ffsll((long long)nz) - 1;
                    nz &= nz - 1;
                    int ii = gg * 64 + b;
                    uint64_t aw = __shfl(active, gg);
                    bool kept = (aw >> b) & 1ull;
                    uint64_t m = (l < 32) ? atomicOr(&mask[(size_t)ii * 32 + l], 0ull) : 0ull;
                    if (kept) active &= ~m;
                }
            }
        }
        if (l < 32) {
            int limit = K_TOP - l * 64;
            int nvec = limit < 64 ? limit / 4 : 16;
            for (int v = 0; v < nvec; ++v) {
                float4 f;
                f.x = ((active >> (4 * v + 0)) & 1ull) ? 1.0f : 0.0f;
                f.y = ((active >> (4 * v + 1)) & 1ull) ? 1.0f : 0.0f;
                f.z = ((active >> (4 * v + 2)) & 1ull) ? 1.0f : 0.0f;
                f.w = ((active >> (4 * v + 3)) & 1ull) ? 1.0f : 0.0f;
                *(float4*)&out[12000 + l * 64 + 4 * v] = f;
            }
        }
    }
    // reset MAGIC words for the next replay (zeroed state is what D1b expects)
    if (t < 8) atomicExch(&zin[t], 0u);
}

extern "C" void kernel_launch(void* const* d_in, const int* in_sizes, int n_in,
                              void* d_out, int out_size, void* d_ws, size_t ws_size,
                              hipStream_t stream) {
    const float* deltas = (const float*)d_in[0];
    const float* locs   = (const float*)d_in[1];
    const float* logits = (const float*)d_in[2];
    const int*   stridep = (const int*)d_in[3];
    float* out = (float*)d_out;
    char* ws = (char*)d_ws;

    uint32_t* mkey = (uint32_t*)(ws + OFF_MKEY);
    uint8_t*  cls  = (uint8_t*)(ws + OFF_CLS);
    uint32_t* hist = (uint32_t*)(ws + OFF_HIST);
    uint32_t* scal = (uint32_t*)(ws + OFF_SCAL);
    unsigned long long* grp = (unsigned long long*)(ws + OFF_GRP);
    uint32_t* zin  = (uint32_t*)(ws + OFF_ZIN);
    unsigned long long* cand = (unsigned long long*)(ws + OFF_CAND);
    uint64_t* mask = (uint64_t*)(ws + OFF_MASK);

    k_scoremax<<<dim3(1024), dim3(256), 0, stream>>>(logits, mkey, cls);
    k_hist<<<dim3(1024), dim3(256), 0, stream>>>(mkey, hist, zin);
    k_compact<<<dim3(256), dim3(256), 0, stream>>>(mkey, hist, scal, cand);
    k_rank<<<dim3(256), dim3(256), 0, stream>>>(cand, scal, deltas, locs, stridep, cls, out);
    k_maskscan<<<dim3(500), dim3(256), 0, stream>>>(out, scal, mask, grp, zin, out);
}

// Round 15
// 90.071 us; speedup vs baseline: 1.5771x; 1.2659x over previous
//
#include <hip/hip_runtime.h>
#include <stdint.h>
#include <math.h>

#pragma clang fp contract(off)

#define N_ROWS 1048576
#define N_CLS  20
#define K_TOP  2000
#define CAND_MAX 8192
#define NBINS  4096
#define H_COPIES 4
#define DELTA_ULP 4096u

// scal slots (dwords) -- inside the zeroed region
#define SC_CNT   0
#define SC_MAXK  1
#define SC_DONE  2   // maskscan done-counter
#define SC_BAR   3   // histcompact arrival counter
#define SC_FLAG  4   // histcompact release flag = Tk+1 (nonzero)

// ws layout
static constexpr size_t OFF_MKEY = 0;                              // u32[N]          4 MB
static constexpr size_t OFF_CLS  = OFF_MKEY + 4ull * N_ROWS;       // u8[N]           1 MB
static constexpr size_t OFF_HIST = OFF_CLS + (size_t)N_ROWS;       // u32[4*4096] -- zero region start
static constexpr size_t OFF_SCAL = OFF_HIST + 4ull * H_COPIES * NBINS;  // u32[16]
static constexpr size_t OFF_GRP  = OFF_SCAL + 64;                  // u64[32]     -- zero region end (16464 dw)
static constexpr size_t OFF_CAND = OFF_GRP + 256;                  // u64[CAND_MAX]
static constexpr size_t OFF_MASK = OFF_CAND + 8ull * CAND_MAX;     // u64[K_TOP*32]

__device__ __forceinline__ uint32_t mono_key(float f) {
    uint32_t u = __float_as_uint(f);
    return u ^ ((u & 0x80000000u) ? 0xFFFFFFFFu : 0x80000000u);
}
__device__ __forceinline__ float mono_inv(uint32_t k) {
    uint32_t u = (k & 0x80000000u) ? (k ^ 0x80000000u) : ~k;
    return __uint_as_float(u);
}

// ---- D1: PURE read+argmax+write (proven sub-fill in R14). Blocks 0..7 additionally
//      zero hist/scal/grp with PLAIN STORES -- no handshake: nothing in this kernel
//      consumes them; the dispatch boundary orders them for D2. (R14 post-mortem:
//      the old zin atomic-poll handshake serialized ~8K RMWs on one line = ~50us.)
__global__ __launch_bounds__(256) void k_scoremax(const float* __restrict__ logits,
                                                  uint32_t* __restrict__ mkey,
                                                  uint8_t* __restrict__ cls,
                                                  uint32_t* __restrict__ zreg) {
    int t = threadIdx.x, b = blockIdx.x;
    if (b < 8) {
#pragma unroll
        for (int k = 0; k < 8; ++k) zreg[b * 256 + t + k * 2048] = 0;   // 16384 dwords
        if (b == 7 && t < 80) zreg[16384 + t] = 0;                      // scal + grp
    }
    size_t r0 = (size_t)b * 1024 + t;              // rows r0, +256, +512, +768
    const float4* p0 = (const float4*)(logits + r0 * N_CLS);
    const float4* p1 = (const float4*)(logits + (r0 + 256) * N_CLS);
    const float4* p2 = (const float4*)(logits + (r0 + 512) * N_CLS);
    const float4* p3 = (const float4*)(logits + (r0 + 768) * N_CLS);
    float4 a0 = p0[0], a1 = p0[1], a2 = p0[2], a3 = p0[3], a4 = p0[4];
    float4 b0 = p1[0], b1 = p1[1], b2 = p1[2], b3 = p1[3], b4 = p1[4];
    float4 c0 = p2[0], c1 = p2[1], c2 = p2[2], c3 = p2[3], c4 = p2[4];
    float4 d0 = p3[0], d1 = p3[1], d2 = p3[2], d3 = p3[3], d4 = p3[4];
    __builtin_amdgcn_sched_barrier(0);             // all 20 loads precede all uses

#define CK(mm, cc, val, idx) if ((val) > mm) { mm = (val); cc = (idx); }
    float mA = a0.x; int cA = 0;
    CK(mA, cA, a0.y, 1)  CK(mA, cA, a0.z, 2)  CK(mA, cA, a0.w, 3)
    CK(mA, cA, a1.x, 4)  CK(mA, cA, a1.y, 5)  CK(mA, cA, a1.z, 6)  CK(mA, cA, a1.w, 7)
    CK(mA, cA, a2.x, 8)  CK(mA, cA, a2.y, 9)  CK(mA, cA, a2.z, 10) CK(mA, cA, a2.w, 11)
    CK(mA, cA, a3.x, 12) CK(mA, cA, a3.y, 13) CK(mA, cA, a3.z, 14) CK(mA, cA, a3.w, 15)
    CK(mA, cA, a4.x, 16) CK(mA, cA, a4.y, 17) CK(mA, cA, a4.z, 18) CK(mA, cA, a4.w, 19)
    float mB = b0.x; int cB = 0;
    CK(mB, cB, b0.y, 1)  CK(mB, cB, b0.z, 2)  CK(mB, cB, b0.w, 3)
    CK(mB, cB, b1.x, 4)  CK(mB, cB, b1.y, 5)  CK(mB, cB, b1.z, 6)  CK(mB, cB, b1.w, 7)
    CK(mB, cB, b2.x, 8)  CK(mB, cB, b2.y, 9)  CK(mB, cB, b2.z, 10) CK(mB, cB, b2.w, 11)
    CK(mB, cB, b3.x, 12) CK(mB, cB, b3.y, 13) CK(mB, cB, b3.z, 14) CK(mB, cB, b3.w, 15)
    CK(mB, cB, b4.x, 16) CK(mB, cB, b4.y, 17) CK(mB, cB, b4.z, 18) CK(mB, cB, b4.w, 19)
    float mC = c0.x; int cC = 0;
    CK(mC, cC, c0.y, 1)  CK(mC, cC, c0.z, 2)  CK(mC, cC, c0.w, 3)
    CK(mC, cC, c1.x, 4)  CK(mC, cC, c1.y, 5)  CK(mC, cC, c1.z, 6)  CK(mC, cC, c1.w, 7)
    CK(mC, cC, c2.x, 8)  CK(mC, cC, c2.y, 9)  CK(mC, cC, c2.z, 10) CK(mC, cC, c2.w, 11)
    CK(mC, cC, c3.x, 12) CK(mC, cC, c3.y, 13) CK(mC, cC, c3.z, 14) CK(mC, cC, c3.w, 15)
    CK(mC, cC, c4.x, 16) CK(mC, cC, c4.y, 17) CK(mC, cC, c4.z, 18) CK(mC, cC, c4.w, 19)
    float mD = d0.x; int cD = 0;
    CK(mD, cD, d0.y, 1)  CK(mD, cD, d0.z, 2)  CK(mD, cD, d0.w, 3)
    CK(mD, cD, d1.x, 4)  CK(mD, cD, d1.y, 5)  CK(mD, cD, d1.z, 6)  CK(mD, cD, d1.w, 7)
    CK(mD, cD, d2.x, 8)  CK(mD, cD, d2.y, 9)  CK(mD, cD, d2.z, 10) CK(mD, cD, d2.w, 11)
    CK(mD, cD, d3.x, 12) CK(mD, cD, d3.y, 13) CK(mD, cD, d3.z, 14) CK(mD, cD, d3.w, 15)
    CK(mD, cD, d4.x, 16) CK(mD, cD, d4.y, 17) CK(mD, cD, d4.z, 18) CK(mD, cD, d4.w, 19)
#undef CK

    mkey[r0]       = mono_key(mA);  cls[r0]       = (uint8_t)cA;
    mkey[r0 + 256] = mono_key(mB);  cls[r0 + 256] = (uint8_t)cB;
    mkey[r0 + 512] = mono_key(mC);  cls[r0 + 512] = (uint8_t)cC;
    mkey[r0 + 768] = mono_key(mD);  cls[r0 + 768] = (uint8_t)cD;
}

// ---- D2: hist + find + compact in ONE kernel via the cheap single-word barrier.
//      256 blocks (1/CU, co-resident by trivial capacity). Each block: 16 keys/thread
//      into registers -> LDS 12-bit hist -> publish (4 spread copies) -> drain ->
//      t==0-only arrival counter; LAST block does find12 (atomic fetches) and
//      publishes Tk+1 as the release flag; all blocks poll ONE word with t==0 only
//      (256 RMWs/round, not R14's 8K), then compact from registers with sigmoid.
__global__ __launch_bounds__(256) void k_histcompact(const uint32_t* __restrict__ mkey,
                                                     uint32_t* __restrict__ hist,
                                                     uint32_t* __restrict__ scal,
                                                     unsigned long long* __restrict__ cand) {
    __shared__ uint32_t hh[NBINS];         // 16 KB (reused as sfx by last block)
    __shared__ uint64_t stg[1024];         // 8 KB compact staging
    __shared__ uint32_t bc;
    __shared__ uint32_t cnt, gbase;
    __shared__ int islast;
    int t = threadIdx.x, b = blockIdx.x;
    int lane = t & 63;
    if (t == 0) cnt = 0;
    for (int i = t; i < NBINS; i += 256) hh[i] = 0;
    __syncthreads();

    // 16 keys/thread, coalesced uint4 loads (kept in registers through the barrier)
    const uint4* m4 = (const uint4*)mkey;
    size_t base = (size_t)b * 1024;                // uint4 index; 4096 rows/block
    uint4 v0 = m4[base + t], v1 = m4[base + 256 + t];
    uint4 v2 = m4[base + 512 + t], v3 = m4[base + 768 + t];
    atomicAdd(&hh[v0.x >> 20], 1u); atomicAdd(&hh[v0.y >> 20], 1u);
    atomicAdd(&hh[v0.z >> 20], 1u); atomicAdd(&hh[v0.w >> 20], 1u);
    atomicAdd(&hh[v1.x >> 20], 1u); atomicAdd(&hh[v1.y >> 20], 1u);
    atomicAdd(&hh[v1.z >> 20], 1u); atomicAdd(&hh[v1.w >> 20], 1u);
    atomicAdd(&hh[v2.x >> 20], 1u); atomicAdd(&hh[v2.y >> 20], 1u);
    atomicAdd(&hh[v2.z >> 20], 1u); atomicAdd(&hh[v2.w >> 20], 1u);
    atomicAdd(&hh[v3.x >> 20], 1u); atomicAdd(&hh[v3.y >> 20], 1u);
    atomicAdd(&hh[v3.z >> 20], 1u); atomicAdd(&hh[v3.w >> 20], 1u);
    __syncthreads();

    // publish nonzero bins (4 spread copies), drain, arrive (t==0 only)
    uint32_t cp = (uint32_t)((b & (H_COPIES - 1)) << 12);
    unsigned long long dummy = 0;
    for (int i = 0; i < 16; ++i) {
        uint32_t h = hh[t * 16 + i];
        if (h) dummy += atomicAdd(&hist[cp + t * 16 + i], h);
    }
    asm volatile("" :: "v"(dummy));
    asm volatile("s_waitcnt vmcnt(0) lgkmcnt(0)" ::: "memory");
    __syncthreads();
    if (t == 0) {
        uint32_t old = atomicAdd(&scal[SC_BAR], 1u);
        islast = (old == 255u) ? 1 : 0;
    }
    __syncthreads();

    if (islast) {
        // find12: thread t sums bins [t*16, t*16+16) over 4 copies via atomic fetches
        uint32_t bv[16]; uint32_t ct = 0;
#pragma unroll
        for (int i = 0; i < 16; ++i) {
            uint32_t s = 0;
#pragma unroll
            for (int k = 0; k < H_COPIES; ++k) s += atomicAdd(&hist[(k << 12) + t * 16 + i], 0u);
            bv[i] = s; ct += s;
        }
        hh[t] = ct;                                 // reuse hh[0..255] as suffix array
        __syncthreads();
        for (int off = 1; off < 256; off <<= 1) {
            uint32_t v = (t + off < 256) ? hh[t + off] : 0;
            __syncthreads();
            hh[t] += v;
            __syncthreads();
        }
        if (hh[t] >= (uint32_t)K_TOP && (t == 255 || hh[t + 1] < (uint32_t)K_TOP)) {
            uint32_t cum = (t == 255) ? 0u : hh[t + 1];
            int i = 15;
            for (; i >= 0; --i) { cum += bv[i]; if (cum >= (uint32_t)K_TOP) break; }
            if (i < 0) i = 0;
            uint32_t tk = ((uint32_t)(t * 16 + i)) << 20;
            // δ-ULP margin: covers rounded-sigmoid ties (~11 key-ULPs) with 370x slack.
            uint32_t Tk = (tk > DELTA_ULP) ? (tk - DELTA_ULP) : 0u;
            atomicExch(&scal[SC_FLAG], Tk + 1u);    // nonzero release word
        }
    }
    // release poll: ONE word, t==0 only, s_sleep backoff
    for (;;) {
        if (t == 0) bc = atomicAdd(&scal[SC_FLAG], 0u);
        __syncthreads();
        if (bc != 0u) break;
        __builtin_amdgcn_s_sleep(32);
    }
    uint32_t T = bc - 1u;

    // compact from registers ((mkey >= T)); sigmoid only for passing rows
#define CSLOT(u, roff) {                                                         \
        uint32_t uu = (u);                                                       \
        bool pass = uu >= T;                                                     \
        unsigned long long bal = __ballot(pass);                                 \
        if (bal) {                                                               \
            uint32_t wbase = 0;                                                  \
            if (lane == 0) wbase = atomicAdd(&cnt, (uint32_t)__popcll(bal));     \
            wbase = __shfl(wbase, 0);                                            \
            if (pass) {                                                          \
                uint32_t pos = wbase + (uint32_t)__popcll(bal & ((1ull << lane) - 1ull)); \
                if (pos < 1024) {                                                \
                    float m = mono_inv(uu);                                      \
                    float ef = (float)exp(-(double)m);                           \
                    float s = 1.0f / (1.0f + ef);                                \
                    stg[pos] = ((uint64_t)(~__float_as_uint(s)) << 32) | (roff); \
                }                                                                \
            }                                                                    \
        }                                                                        \
    }
    uint32_t rb = (uint32_t)((base + t) * 4);
    CSLOT(v0.x, rb + 0) CSLOT(v0.y, rb + 1) CSLOT(v0.z, rb + 2) CSLOT(v0.w, rb + 3)
    rb = (uint32_t)((base + 256 + t) * 4);
    CSLOT(v1.x, rb + 0) CSLOT(v1.y, rb + 1) CSLOT(v1.z, rb + 2) CSLOT(v1.w, rb + 3)
    rb = (uint32_t)((base + 512 + t) * 4);
    CSLOT(v2.x, rb + 0) CSLOT(v2.y, rb + 1) CSLOT(v2.z, rb + 2) CSLOT(v2.w, rb + 3)
    rb = (uint32_t)((base + 768 + t) * 4);
    CSLOT(v3.x, rb + 0) CSLOT(v3.y, rb + 1) CSLOT(v3.z, rb + 2) CSLOT(v3.w, rb + 3)
#undef CSLOT
    __syncthreads();
    uint32_t n = cnt; if (n > 1024) n = 1024;
    if (t == 0 && n) gbase = atomicAdd(&scal[SC_CNT], n);
    __syncthreads();
    if (n) {
        uint32_t gb = gbase;
        for (uint32_t i = t; i < n; i += 256) {
            uint32_t pos = gb + i;
            if (pos < (uint32_t)CAND_MAX) cand[pos] = stg[i];  // plain store; boundary = coherence
        }
    }
}

// ---- D3: rank-by-counting, M-insensitive (proven R11): cand[] already holds final
//      keys -> LDS fill is a straight copy. 256 blocks x 4 waves; inner scan 4-way
//      unrolled for LDS ILP.
__global__ __launch_bounds__(256) void k_rank(const unsigned long long* __restrict__ cand,
                                              uint32_t* __restrict__ scal,
                                              const float* __restrict__ deltas,
                                              const float* __restrict__ locs,
                                              const int* __restrict__ stridep,
                                              const uint8_t* __restrict__ cls,
                                              float* __restrict__ out) {
    __shared__ uint64_t keys[CAND_MAX];   // 64 KB
    int t = threadIdx.x;
    uint32_t M = scal[SC_CNT];
    if (M > (uint32_t)CAND_MAX) M = CAND_MAX;
    for (uint32_t i = t; i < M; i += 256) keys[i] = cand[i];
    __syncthreads();
    int wid = t >> 6, lane = t & 63;
    float stridef = (float)(*stridep);
    float wmx = -3.4e38f;
    for (uint32_t c = (uint32_t)blockIdx.x * 4 + wid; c < M; c += 1024) {
        uint64_t myk = keys[c];
        uint32_t r = 0;
        uint32_t j = lane;
        for (; j + 192 < M; j += 256) {             // 4 independent LDS reads -> pipelined
            uint64_t k0 = keys[j], k1 = keys[j + 64], k2 = keys[j + 128], k3 = keys[j + 192];
            r += (uint32_t)(k0 < myk) + (uint32_t)(k1 < myk)
               + (uint32_t)(k2 < myk) + (uint32_t)(k3 < myk);
        }
        for (; j < M; j += 64) r += (keys[j] < myk) ? 1u : 0u;
#pragma unroll
        for (int o = 32; o > 0; o >>= 1) r += __shfl_down(r, o);
        if (lane == 0 && r < (uint32_t)K_TOP) {
            uint32_t row = (uint32_t)myk & (N_ROWS - 1);
            float s = __uint_as_float(~(uint32_t)(myk >> 32));
            float4 dl = ((const float4*)deltas)[row];
            float2 lc = ((const float2*)locs)[row];
            float d0 = dl.x * stridef, d1 = dl.y * stridef, d2 = dl.z * stridef, d3 = dl.w * stridef;
            float b0f = lc.x - d0, b1f = lc.y - d1, b2f = lc.x + d2, b3f = lc.y + d3;
            float4 bx = { b0f, b1f, b2f, b3f };
            *(float4*)&out[4 * r] = bx;
            out[8000 + r] = s;
            out[10000 + r] = (float)cls[row];
            wmx = fmaxf(wmx, fmaxf(fmaxf(b0f, b1f), fmaxf(b2f, b3f)));
        }
    }
    if (lane == 0) atomicMax(&scal[SC_MAXK], mono_key(wmx));
}

// ---- D4: pairwise suppression mask (quirky IoU replicated exactly) + fused scan.
//      Skip-empty rows (grp-gated). Atomic-only handoff (proven R5/R7/R8).
__global__ __launch_bounds__(256) void k_maskscan(const float* __restrict__ out_ro,
                                                  uint32_t* __restrict__ scal,
                                                  uint64_t* __restrict__ mask,
                                                  unsigned long long* __restrict__ grp,
                                                  float* __restrict__ out) {
    __shared__ uint64_t wb[4][32];
    __shared__ int lastdone;
    int t = threadIdx.x;
    int lane = t & 63;
    int wid = t >> 6;
    int i = blockIdx.x * 4 + wid;                   // 2000 waves total
    float off1 = mono_inv(scal[SC_MAXK]) + 1.0f;    // max_coord + 1 (prev dispatch, coherent)
    float4 boxi = *(const float4*)&out_ro[4 * i];
    float oi = out_ro[10000 + i] * off1;
    float x1i = boxi.x + oi, y2i = boxi.y + oi, x2i = boxi.z + oi, y1i = boxi.w + oi;
    float ai = (x2i - x1i) * (y2i - y1i);
    uint64_t any = 0;
    for (int jb = 0; jb < 32; ++jb) {
        int j = jb * 64 + lane;
        bool sup = false;
        if (j < K_TOP && j > i) {
            float4 boxj = *(const float4*)&out_ro[4 * j];
            float oj = out_ro[10000 + j] * off1;
            float x1j = boxj.x + oj, y2j = boxj.y + oj, x2j = boxj.z + oj, y1j = boxj.w + oj;
            float aj = (x2j - x1j) * (y2j - y1j);
            float xx1 = fmaxf(x1i, x1j);
            float yy1 = fminf(y1i, y1j);
            float xx2 = fminf(x2i, x2j);
            float yy2 = fmaxf(y2i, y2j);
            float inter = fabsf(xx2 - xx1) * fabsf(yy2 - yy1);
            float iou = inter / ((ai + aj) - inter);
            sup = iou > 0.5f;
        }
        unsigned long long bits = __ballot(sup);
        if (lane == 0) wb[wid][jb] = bits;
        any |= bits;
    }
    unsigned long long dummy = 0;
    if (lane == 0 && any) {                         // rare: NMS barely suppresses here
        for (int jb = 0; jb < 32; ++jb)
            dummy += atomicExch(&mask[(size_t)i * 32 + jb], wb[wid][jb]);
        dummy += atomicOr(&grp[i >> 6], 1ull << (i & 63));
    }
    asm volatile("" :: "v"(dummy));                 // force atomic returns (vmcnt drained)
    asm volatile("s_waitcnt vmcnt(0) lgkmcnt(0)" ::: "memory");
    __syncthreads();
    if (t == 0) {
        unsigned old = atomicAdd(&scal[SC_DONE], 1u);
        lastdone = (old == (unsigned)(gridDim.x - 1)) ? 1 : 0;
    }
    __syncthreads();
    if (!lastdone) return;

    if (t < 64) {
        int l = t;                                  // lane w<32 holds active word w
        uint64_t g = (l < 32) ? atomicOr(&grp[l], 0ull) : 0ull;
        uint64_t active = ~0ull;
        if (__ballot(g != 0ull)) {
            for (int gg = 0; gg < 32; ++gg) {
                uint64_t nz = __shfl(g, gg);
                while (nz) {
                    int b = __ffsll((long long)nz) - 1;
                    nz &= nz - 1;
                    int ii = gg * 64 + b;
                    uint64_t aw = __shfl(active, gg);
                    bool kept = (aw >> b) & 1ull;
                    uint64_t m = (l < 32) ? atomicOr(&mask[(size_t)ii * 32 + l], 0ull) : 0ull;
                    if (kept) active &= ~m;
                }
            }
        }
        if (l < 32) {
            int limit = K_TOP - l * 64;
            int nvec = limit < 64 ? limit / 4 : 16;
            for (int v = 0; v < nvec; ++v) {
                float4 f;
                f.x = ((active >> (4 * v + 0)) & 1ull) ? 1.0f : 0.0f;
                f.y = ((active >> (4 * v + 1)) & 1ull) ? 1.0f : 0.0f;
                f.z = ((active >> (4 * v + 2)) & 1ull) ? 1.0f : 0.0f;
                f.w = ((active >> (4 * v + 3)) & 1ull) ? 1.0f : 0.0f;
                *(float4*)&out[12000 + l * 64 + 4 * v] = f;
            }
        }
    }
}

extern "C" void kernel_launch(void* const* d_in, const int* in_sizes, int n_in,
                              void* d_out, int out_size, void* d_ws, size_t ws_size,
                              hipStream_t stream) {
    const float* deltas = (const float*)d_in[0];
    const float* locs   = (const float*)d_in[1];
    const float* logits = (const float*)d_in[2];
    const int*   stridep = (const int*)d_in[3];
    float* out = (float*)d_out;
    char* ws = (char*)d_ws;

    uint32_t* mkey = (uint32_t*)(ws + OFF_MKEY);
    uint8_t*  cls  = (uint8_t*)(ws + OFF_CLS);
    uint32_t* hist = (uint32_t*)(ws + OFF_HIST);
    uint32_t* scal = (uint32_t*)(ws + OFF_SCAL);
    unsigned long long* grp = (unsigned long long*)(ws + OFF_GRP);
    unsigned long long* cand = (unsigned long long*)(ws + OFF_CAND);
    uint64_t* mask = (uint64_t*)(ws + OFF_MASK);

    k_scoremax<<<dim3(1024), dim3(256), 0, stream>>>(logits, mkey, cls, hist);
    k_histcompact<<<dim3(256), dim3(256), 0, stream>>>(mkey, hist, scal, cand);
    k_rank<<<dim3(256), dim3(256), 0, stream>>>(cand, scal, deltas, locs, stridep, cls, out);
    k_maskscan<<<dim3(500), dim3(256), 0, stream>>>(out, scal, mask, grp, out);
}